// Round 7
// baseline (260.179 us; speedup 1.0000x reference)
//
#include <hip/hip_runtime.h>
#include <hip/hip_cooperative_groups.h>

namespace cg = cooperative_groups;

#define D 128

typedef __attribute__((ext_vector_type(8))) short short8;
typedef __attribute__((ext_vector_type(4))) float f32x4;

// ---------- bf16 helpers (manual, RNE) ----------
static __device__ __forceinline__ unsigned short f2bf(float f) {
    unsigned int u = __float_as_uint(f);
    u += 0x7fffu + ((u >> 16) & 1u);
    return (unsigned short)(u >> 16);
}
static __device__ __forceinline__ float bf_lo(unsigned int v) {
    return __uint_as_float(v << 16);
}
static __device__ __forceinline__ float bf_hi(unsigned int v) {
    return __uint_as_float(v & 0xffff0000u);
}

// ---------- cooperative CSR build: zero + count + dinv + scan + fill ----------
// Fixed geometry: 256 blocks x 256 threads (all co-resident on 256 CUs).
__global__ __launch_bounds__(256) void build_k(const int* __restrict__ ei,
                                               int* __restrict__ cnt,
                                               int* __restrict__ rowstart,
                                               int* __restrict__ cursor,
                                               float* __restrict__ dinv,
                                               int* __restrict__ eidx,
                                               int* __restrict__ bsum,
                                               int E, int N) {
    cg::grid_group grid = cg::this_grid();
    const int NT = 256 * 256;
    int t = threadIdx.x;
    int tid = blockIdx.x * 256 + t;
    const int* dst = ei + E;

    // phase 0: zero cnt
    for (int i = tid; i < N; i += NT) cnt[i] = 0;
    grid.sync();

    // phase 1: degree count (coalesced grid-stride)
    for (int e = tid; e < E; e += NT) atomicAdd(&cnt[dst[e]], 1);
    grid.sync();

    // phase 2: per-thread chunk (2 elems) sums + dinv; block scan; bsum
    __shared__ int sh[256];
    __shared__ int sb[256];
    int base = tid * 2;
    int v0 = (base < N) ? cnt[base] : 0;
    int v1 = (base + 1 < N) ? cnt[base + 1] : 0;
    if (base < N) dinv[base] = rsqrtf((float)v0 + 1.0f);
    if (base + 1 < N) dinv[base + 1] = rsqrtf((float)v1 + 1.0f);
    int ts = v0 + v1;
    sh[t] = ts;
    __syncthreads();
    for (int off = 1; off < 256; off <<= 1) {
        int u = (t >= off) ? sh[t - off] : 0;
        __syncthreads();
        sh[t] += u;
        __syncthreads();
    }
    int run_local = sh[t] - ts;  // exclusive prefix within block chunk
    if (t == 255) bsum[blockIdx.x] = sh[255];
    grid.sync();

    // phase 3: every block scans all 256 bsums locally -> its block offset
    sb[t] = bsum[t];
    __syncthreads();
    for (int off = 1; off < 256; off <<= 1) {
        int u = (t >= off) ? sb[t - off] : 0;
        __syncthreads();
        sb[t] += u;
        __syncthreads();
    }
    int boff_blk = (blockIdx.x > 0) ? sb[blockIdx.x - 1] : 0;
    int total = sb[255];

    int run = run_local + boff_blk;
    if (base < N)     { rowstart[base] = run; cursor[base] = run; }
    run += v0;
    if (base + 1 < N) { rowstart[base + 1] = run; cursor[base + 1] = run; }
    if (tid == 0) rowstart[N] = total;  // == E
    grid.sync();

    // phase 4: fill CSR (absolute cursor)
    for (int e = tid; e < E; e += NT) {
        int s = ei[e];
        int d = dst[e];
        int p = atomicAdd(&cursor[d], 1);
        eidx[p] = s;
    }
}

// ---------- MFMA GEMM: hs = (x @ W) * dinv[row], stored bf16 ----------
__global__ __launch_bounds__(256) void gemm_mfma(const float* __restrict__ x,
                                                 const float* __restrict__ W,
                                                 const float* __restrict__ dinv,
                                                 unsigned short* __restrict__ h,
                                                 int N) {
    __shared__ unsigned short Wt[D * D];       // transposed W, bf16, XOR-swizzled (32 KB)
    __shared__ unsigned short ost[4][16 * D];  // per-wave output stage (16 KB)

    int t = threadIdx.x;
    int w = t >> 6, l = t & 63;
    int mrow = l & 15, kgrp = l >> 4;

    // ---- stage Wt[c][k] = bf16(W[k][c]), swizzled: byte ^= (c&7)<<4 ----
    {
        const float4* Wv = (const float4*)W;
        for (int i = 0; i < 16; ++i) {
            int idx = i * 256 + t;       // 4096 float4 total
            int k = idx >> 5;            // W row
            int c0 = (idx & 31) * 4;     // W col
            float4 v = Wv[idx];
            float vv[4] = {v.x, v.y, v.z, v.w};
#pragma unroll
            for (int j = 0; j < 4; ++j) {
                int c = c0 + j;
                unsigned int B = (unsigned int)c * 256 + (unsigned int)k * 2;
                unsigned int sB = B ^ (((unsigned int)c & 7u) << 4);
                *(unsigned short*)((char*)Wt + sB) = f2bf(vv[j]);
            }
        }
    }
    __syncthreads();

    for (int rt = 0; rt < 4; ++rt) {
        int row0 = blockIdx.x * 256 + w * 64 + rt * 16;  // N % 16 == 0
        bool act = row0 < N;

        if (act) {
            short8 a[4];
#pragma unroll
            for (int kk = 0; kk < 4; ++kk) {
                const float* p = &x[(size_t)(row0 + mrow) * D + kk * 32 + kgrp * 8];
                float4 q0 = *(const float4*)p;
                float4 q1 = *(const float4*)(p + 4);
                short8 af;
                af[0] = (short)f2bf(q0.x); af[1] = (short)f2bf(q0.y);
                af[2] = (short)f2bf(q0.z); af[3] = (short)f2bf(q0.w);
                af[4] = (short)f2bf(q1.x); af[5] = (short)f2bf(q1.y);
                af[6] = (short)f2bf(q1.z); af[7] = (short)f2bf(q1.w);
                a[kk] = af;
            }
            f32x4 acc[8];
#pragma unroll
            for (int nt = 0; nt < 8; ++nt) {
                acc[nt] = (f32x4){0.f, 0.f, 0.f, 0.f};
#pragma unroll
                for (int kk = 0; kk < 4; ++kk) {
                    unsigned int c = nt * 16 + mrow;
                    unsigned int B = c * 256 + (unsigned int)(kk * 32 + kgrp * 8) * 2;
                    unsigned int sB = B ^ ((c & 7u) << 4);
                    short8 bf = *(const short8*)((char*)Wt + sB);
                    acc[nt] = __builtin_amdgcn_mfma_f32_16x16x32_bf16(a[kk], bf, acc[nt], 0, 0, 0);
                }
            }
            float dv[4];
#pragma unroll
            for (int j = 0; j < 4; ++j) dv[j] = dinv[row0 + kgrp * 4 + j];
#pragma unroll
            for (int nt = 0; nt < 8; ++nt)
#pragma unroll
                for (int j = 0; j < 4; ++j) {
                    int rr = kgrp * 4 + j;
                    ost[w][rr * D + nt * 16 + mrow] = f2bf(acc[nt][j] * dv[j]);
                }
        }
        __syncthreads();
        if (act) {
            const uint4* os4 = (const uint4*)ost[w];
            uint4* H4 = (uint4*)h;
#pragma unroll
            for (int i2 = 0; i2 < 4; ++i2) {
                int e = i2 * 64 + l;
                H4[(size_t)row0 * 16 + e] = os4[e];
            }
        }
        __syncthreads();
    }
}

// ---------- pull-mode aggregate + bias + relu + residual (fused) ----------
// hs rows pre-scaled by dinv[src]; agg = di * (hs[i] + sum hs[src])
// ALL loop conditions wave-uniform so every __shfl runs with the full
// 64-lane exec mask (masked-lane shfl was the round-3/4 bug).
__global__ __launch_bounds__(256) void agg_k(const unsigned int* __restrict__ h2,
                                             const float* __restrict__ x,
                                             const float* __restrict__ b,
                                             const float* __restrict__ dinv,
                                             const int* __restrict__ rowstart,
                                             const int* __restrict__ eidx,
                                             float* __restrict__ out, int N) {
    int w = threadIdx.x >> 6;
    int lane = threadIdx.x & 63;
    int half = lane >> 5;
    int sl = lane & 31;
    int i = blockIdx.x * 4 + w;
    if (i >= N) return;

    int rs = rowstart[i];
    int re = rowstart[i + 1];
    int deg = re - rs;   // wave-uniform
    float di = dinv[i];

    const uint2* H = (const uint2*)h2;

    int idxv = 0;
    if (lane < deg) idxv = eidx[rs + lane];

    float a0 = 0.f, a1 = 0.f, a2 = 0.f, a3 = 0.f;
    if (half == 0) {  // self-loop row: half-wave covers the full 256B row
        uint2 sv = H[(size_t)i * 32 + sl];
        a0 = bf_lo(sv.x); a1 = bf_hi(sv.x);
        a2 = bf_lo(sv.y); a3 = bf_hi(sv.y);
    }

    int dk = deg < 64 ? deg : 64;  // wave-uniform
    int k = 0;
    for (; k + 3 < dk; k += 4) {
        int sA = __shfl(idxv, k + half, 64);
        int sB = __shfl(idxv, k + 2 + half, 64);
        uint2 vA = H[(size_t)sA * 32 + sl];
        uint2 vB = H[(size_t)sB * 32 + sl];
        a0 += bf_lo(vA.x) + bf_lo(vB.x);
        a1 += bf_hi(vA.x) + bf_hi(vB.x);
        a2 += bf_lo(vA.y) + bf_lo(vB.y);
        a3 += bf_hi(vA.y) + bf_hi(vB.y);
    }
    if (k + 1 < dk) {
        int sA = __shfl(idxv, k + half, 64);
        uint2 vA = H[(size_t)sA * 32 + sl];
        a0 += bf_lo(vA.x); a1 += bf_hi(vA.x);
        a2 += bf_lo(vA.y); a3 += bf_hi(vA.y);
        k += 2;
    }
    if (k < dk) {
        int sA = __shfl(idxv, k, 64);
        if (half == 0) {
            uint2 vA = H[(size_t)sA * 32 + sl];
            a0 += bf_lo(vA.x); a1 += bf_hi(vA.x);
            a2 += bf_lo(vA.y); a3 += bf_hi(vA.y);
        }
    }
    for (int p = 64 + half; p < deg; p += 2) {  // rare: deg > 64
        int sA = eidx[rs + p];
        uint2 vA = H[(size_t)sA * 32 + sl];
        a0 += bf_lo(vA.x); a1 += bf_hi(vA.x);
        a2 += bf_lo(vA.y); a3 += bf_hi(vA.y);
    }

    a0 += __shfl_xor(a0, 32, 64);
    a1 += __shfl_xor(a1, 32, 64);
    a2 += __shfl_xor(a2, 32, 64);
    a3 += __shfl_xor(a3, 32, 64);

    if (half == 0) {
        float4 bb = *(const float4*)&b[sl * 4];
        // x read-once and out never-re-read: NT via ext-vector f32x4
        // (__builtin_nontemporal_* rejects HIP_vector_type pointers)
        const f32x4* px = (const f32x4*)&x[(size_t)i * D + sl * 4];
        f32x4 xx = __builtin_nontemporal_load(px);
        f32x4 o;
        o.x = xx.x + fmaxf(a0 * di + bb.x, 0.f);
        o.y = xx.y + fmaxf(a1 * di + bb.y, 0.f);
        o.z = xx.z + fmaxf(a2 * di + bb.z, 0.f);
        o.w = xx.w + fmaxf(a3 * di + bb.w, 0.f);
        f32x4* po = (f32x4*)&out[(size_t)i * D + sl * 4];
        __builtin_nontemporal_store(o, po);
    }
}

extern "C" void kernel_launch(void* const* d_in, const int* in_sizes, int n_in,
                              void* d_out, int out_size, void* d_ws, size_t ws_size,
                              hipStream_t stream) {
    const int* ei = (const int*)d_in[1];
    const float* x = (const float*)d_in[0];
    const float* W = (const float*)d_in[2];
    const float* b = (const float*)d_in[3];
    float* out = (float*)d_out;

    int N = in_sizes[0] / D;
    int E = in_sizes[1] / 2;

    char* ws = (char*)d_ws;
    float* dinv      = (float*)(ws + 0);
    int* cnt         = (int*)(ws + (512 << 10));
    int* rowstart    = (int*)(ws + (1024 << 10));
    int* cursor      = (int*)(ws + (1536 << 10));
    int* bsum        = (int*)(ws + (2048 << 10));
    int* eidx        = (int*)(ws + (2056 << 10));             // E*4 = 2.44 MB
    unsigned short* h = (unsigned short*)(ws + (4608 << 10)); // N*128*2 = 24.4 MB
    unsigned int* h2 = (unsigned int*)h;

    {
        void* args[] = {(void*)&ei, (void*)&cnt, (void*)&rowstart, (void*)&cursor,
                        (void*)&dinv, (void*)&eidx, (void*)&bsum,
                        (void*)&E, (void*)&N};
        hipError_t err = hipLaunchCooperativeKernel((void*)build_k, dim3(256), dim3(256),
                                                    args, 0, stream);
        (void)err;
    }
    gemm_mfma<<<(N + 255) / 256, 256, 0, stream>>>(x, W, dinv, h, N);
    agg_k<<<(N + 3) / 4, 256, 0, stream>>>(h2, x, b, dinv, rowstart, eidx, out, N);
}

// Round 8
// 159.418 us; speedup vs baseline: 1.6320x; 1.6320x over previous
//
#include <hip/hip_runtime.h>

#define D 128

typedef __attribute__((ext_vector_type(8))) short short8;
typedef __attribute__((ext_vector_type(4))) float f32x4;

// ---------- bf16 helpers (manual, RNE) ----------
static __device__ __forceinline__ unsigned short f2bf(float f) {
    unsigned int u = __float_as_uint(f);
    u += 0x7fffu + ((u >> 16) & 1u);
    return (unsigned short)(u >> 16);
}
static __device__ __forceinline__ float bf_lo(unsigned int v) {
    return __uint_as_float(v << 16);
}
static __device__ __forceinline__ float bf_hi(unsigned int v) {
    return __uint_as_float(v & 0xffff0000u);
}

// ---------- MFMA GEMM: hs = (x @ W) * dinv[row], stored bf16 ----------
// 64 rows/block, ONE 16-row tile per wave (no rt loop, no inter-tile barrier).
// A frag (16x32): lane l holds x[row0 + (l&15)][kk*32 + (l>>4)*8 + j]
// B frag (32x16): lane l holds W[kk*32 + (l>>4)*8 + j][nt*16 + (l&15)]
// D (16x16):      lane l holds h[row0 + (l>>4)*4 + j][nt*16 + (l&15)]
__global__ __launch_bounds__(256) void gemm_mfma(const float* __restrict__ x,
                                                 const float* __restrict__ W,
                                                 const float* __restrict__ dinv,
                                                 unsigned short* __restrict__ h,
                                                 int N) {
    __shared__ unsigned short Wt[D * D];       // transposed W, bf16, XOR-swizzled (32 KB)
    __shared__ unsigned short ost[4][16 * D];  // per-wave output stage (16 KB)

    int t = threadIdx.x;
    int w = t >> 6, l = t & 63;
    int mrow = l & 15, kgrp = l >> 4;

    // ---- stage Wt[c][k] = bf16(W[k][c]), swizzled: byte ^= (c&7)<<4 ----
    // W is L2-hot after the first rank of blocks (64 KB, read by all 1563 blocks).
    {
        const float4* Wv = (const float4*)W;
#pragma unroll
        for (int i = 0; i < 16; ++i) {
            int idx = i * 256 + t;       // 4096 float4 total
            int k = idx >> 5;            // W row
            int c0 = (idx & 31) * 4;     // W col
            float4 v = Wv[idx];
            float vv[4] = {v.x, v.y, v.z, v.w};
#pragma unroll
            for (int j = 0; j < 4; ++j) {
                int c = c0 + j;
                unsigned int B = (unsigned int)c * 256 + (unsigned int)k * 2;
                unsigned int sB = B ^ (((unsigned int)c & 7u) << 4);
                *(unsigned short*)((char*)Wt + sB) = f2bf(vv[j]);
            }
        }
    }
    __syncthreads();

    int row0 = blockIdx.x * 64 + w * 16;  // N % 16 == 0
    if (row0 >= N) return;

    short8 a[4];
#pragma unroll
    for (int kk = 0; kk < 4; ++kk) {
        const float* p = &x[(size_t)(row0 + mrow) * D + kk * 32 + kgrp * 8];
        float4 q0 = *(const float4*)p;
        float4 q1 = *(const float4*)(p + 4);
        short8 af;
        af[0] = (short)f2bf(q0.x); af[1] = (short)f2bf(q0.y);
        af[2] = (short)f2bf(q0.z); af[3] = (short)f2bf(q0.w);
        af[4] = (short)f2bf(q1.x); af[5] = (short)f2bf(q1.y);
        af[6] = (short)f2bf(q1.z); af[7] = (short)f2bf(q1.w);
        a[kk] = af;
    }
    f32x4 acc[8];
#pragma unroll
    for (int nt = 0; nt < 8; ++nt) {
        acc[nt] = (f32x4){0.f, 0.f, 0.f, 0.f};
#pragma unroll
        for (int kk = 0; kk < 4; ++kk) {
            unsigned int c = nt * 16 + mrow;
            unsigned int B = c * 256 + (unsigned int)(kk * 32 + kgrp * 8) * 2;
            unsigned int sB = B ^ ((c & 7u) << 4);
            short8 bf = *(const short8*)((char*)Wt + sB);
            acc[nt] = __builtin_amdgcn_mfma_f32_16x16x32_bf16(a[kk], bf, acc[nt], 0, 0, 0);
        }
    }
    // epilogue: scale by dinv[row], cvt bf16, stage to THIS WAVE's ost slice.
    // ost[w] is wave-private; write->read dependency is same-wave, same-array —
    // compiler inserts the lgkmcnt wait (no block barrier needed).
    float dv[4];
#pragma unroll
    for (int j = 0; j < 4; ++j) dv[j] = dinv[row0 + kgrp * 4 + j];
#pragma unroll
    for (int nt = 0; nt < 8; ++nt)
#pragma unroll
        for (int j = 0; j < 4; ++j) {
            int rr = kgrp * 4 + j;
            ost[w][rr * D + nt * 16 + mrow] = f2bf(acc[nt][j] * dv[j]);
        }
    {
        const uint4* os4 = (const uint4*)ost[w];
        uint4* H4 = (uint4*)h;
#pragma unroll
        for (int i2 = 0; i2 < 4; ++i2) {
            int e = i2 * 64 + l;
            H4[(size_t)row0 * 16 + e] = os4[e];
        }
    }
}

// ---------- degree count over dst (vectorized) ----------
__global__ void count_k(const int* __restrict__ dst, int* __restrict__ cnt, int E) {
    int e = (blockIdx.x * blockDim.x + threadIdx.x) * 4;
    if (e + 3 < E) {
        int4 d = *(const int4*)&dst[e];
        atomicAdd(&cnt[d.x], 1);
        atomicAdd(&cnt[d.y], 1);
        atomicAdd(&cnt[d.z], 1);
        atomicAdd(&cnt[d.w], 1);
    } else {
        for (int q = e; q < E; ++q) atomicAdd(&cnt[dst[q]], 1);
    }
}

// ---------- scan phase A + fused dinv ----------
__global__ __launch_bounds__(256) void scan_a(const int* __restrict__ cnt,
                                              int* __restrict__ rowstart,
                                              int* __restrict__ bsum,
                                              float* __restrict__ dinv, int N) {
    __shared__ int sh[256];
    int t = threadIdx.x;
    int base = blockIdx.x * 1024 + t * 4;
    int v[4];
#pragma unroll
    for (int j = 0; j < 4; ++j) v[j] = (base + j < N) ? cnt[base + j] : 0;
#pragma unroll
    for (int j = 0; j < 4; ++j)
        if (base + j < N) dinv[base + j] = rsqrtf((float)v[j] + 1.0f);
    int ts = v[0] + v[1] + v[2] + v[3];
    sh[t] = ts;
    __syncthreads();
    for (int off = 1; off < 256; off <<= 1) {
        int u = (t >= off) ? sh[t - off] : 0;
        __syncthreads();
        sh[t] += u;
        __syncthreads();
    }
    int run = sh[t] - ts;
#pragma unroll
    for (int j = 0; j < 4; ++j) {
        if (base + j < N) rowstart[base + j] = run;
        run += v[j];
    }
    if (t == 255) bsum[blockIdx.x] = sh[255];
}

__global__ void scan_b(const int* __restrict__ bsum, int* __restrict__ boff,
                       int nb, int* __restrict__ rowstart, int N) {
    __shared__ int sh[128];
    int t = threadIdx.x;
    int v = (t < nb) ? bsum[t] : 0;
    sh[t] = v;
    __syncthreads();
    for (int off = 1; off < 128; off <<= 1) {
        int u = (t >= off) ? sh[t - off] : 0;
        __syncthreads();
        sh[t] += u;
        __syncthreads();
    }
    if (t < nb) boff[t] = sh[t] - v;
    if (t == 127) rowstart[N] = sh[127];
}

// finalize rowstart and init cursor = rowstart (absolute fill positions)
__global__ void scan_c(int* __restrict__ rowstart, const int* __restrict__ boff,
                       int* __restrict__ cursor, int N) {
    int i = blockIdx.x * blockDim.x + threadIdx.x;
    if (i < N) {
        int r = rowstart[i] + boff[i >> 10];
        rowstart[i] = r;
        cursor[i] = r;
    }
}

// ---------- fill CSR edge lists (src per dst), absolute cursor ----------
__global__ void fill_k(const int* __restrict__ ei, int* __restrict__ cursor,
                       int* __restrict__ eidx, int E) {
    int e = blockIdx.x * blockDim.x + threadIdx.x;
    if (e < E) {
        int s = ei[e];
        int d = ei[E + e];
        int p = atomicAdd(&cursor[d], 1);
        eidx[p] = s;
    }
}

// ---------- pull-mode aggregate + bias + relu + residual (fused) ----------
// hs rows pre-scaled by dinv[src]; agg = di * (hs[i] + sum hs[src])
// ALL loop conditions wave-uniform so every __shfl runs with the full
// 64-lane exec mask (masked-lane shfl was the round-3/4 bug).
__global__ __launch_bounds__(256) void agg_k(const unsigned int* __restrict__ h2,
                                             const float* __restrict__ x,
                                             const float* __restrict__ b,
                                             const float* __restrict__ dinv,
                                             const int* __restrict__ rowstart,
                                             const int* __restrict__ eidx,
                                             float* __restrict__ out, int N) {
    int w = threadIdx.x >> 6;
    int lane = threadIdx.x & 63;
    int half = lane >> 5;
    int sl = lane & 31;
    int i = blockIdx.x * 4 + w;
    if (i >= N) return;

    int rs = rowstart[i];
    int re = rowstart[i + 1];
    int deg = re - rs;   // wave-uniform
    float di = dinv[i];

    const uint2* H = (const uint2*)h2;

    int idxv = 0;
    if (lane < deg) idxv = eidx[rs + lane];

    float a0 = 0.f, a1 = 0.f, a2 = 0.f, a3 = 0.f;
    if (half == 0) {  // self-loop row: half-wave covers the full 256B row
        uint2 sv = H[(size_t)i * 32 + sl];
        a0 = bf_lo(sv.x); a1 = bf_hi(sv.x);
        a2 = bf_lo(sv.y); a3 = bf_hi(sv.y);
    }

    int dk = deg < 64 ? deg : 64;  // wave-uniform
    int k = 0;
    for (; k + 3 < dk; k += 4) {
        int sA = __shfl(idxv, k + half, 64);
        int sB = __shfl(idxv, k + 2 + half, 64);
        uint2 vA = H[(size_t)sA * 32 + sl];
        uint2 vB = H[(size_t)sB * 32 + sl];
        a0 += bf_lo(vA.x) + bf_lo(vB.x);
        a1 += bf_hi(vA.x) + bf_hi(vB.x);
        a2 += bf_lo(vA.y) + bf_lo(vB.y);
        a3 += bf_hi(vA.y) + bf_hi(vB.y);
    }
    if (k + 1 < dk) {
        int sA = __shfl(idxv, k + half, 64);
        uint2 vA = H[(size_t)sA * 32 + sl];
        a0 += bf_lo(vA.x); a1 += bf_hi(vA.x);
        a2 += bf_lo(vA.y); a3 += bf_hi(vA.y);
        k += 2;
    }
    if (k < dk) {
        int sA = __shfl(idxv, k, 64);
        if (half == 0) {
            uint2 vA = H[(size_t)sA * 32 + sl];
            a0 += bf_lo(vA.x); a1 += bf_hi(vA.x);
            a2 += bf_lo(vA.y); a3 += bf_hi(vA.y);
        }
    }
    for (int p = 64 + half; p < deg; p += 2) {  // rare: deg > 64
        int sA = eidx[rs + p];
        uint2 vA = H[(size_t)sA * 32 + sl];
        a0 += bf_lo(vA.x); a1 += bf_hi(vA.x);
        a2 += bf_lo(vA.y); a3 += bf_hi(vA.y);
    }

    a0 += __shfl_xor(a0, 32, 64);
    a1 += __shfl_xor(a1, 32, 64);
    a2 += __shfl_xor(a2, 32, 64);
    a3 += __shfl_xor(a3, 32, 64);

    if (half == 0) {
        float4 bb = *(const float4*)&b[sl * 4];
        // x read-once and out never-re-read: NT via ext-vector f32x4
        const f32x4* px = (const f32x4*)&x[(size_t)i * D + sl * 4];
        f32x4 xx = __builtin_nontemporal_load(px);
        f32x4 o;
        o.x = xx.x + fmaxf(a0 * di + bb.x, 0.f);
        o.y = xx.y + fmaxf(a1 * di + bb.y, 0.f);
        o.z = xx.z + fmaxf(a2 * di + bb.z, 0.f);
        o.w = xx.w + fmaxf(a3 * di + bb.w, 0.f);
        f32x4* po = (f32x4*)&out[(size_t)i * D + sl * 4];
        __builtin_nontemporal_store(o, po);
    }
}

extern "C" void kernel_launch(void* const* d_in, const int* in_sizes, int n_in,
                              void* d_out, int out_size, void* d_ws, size_t ws_size,
                              hipStream_t stream) {
    const float* x = (const float*)d_in[0];
    const int* ei = (const int*)d_in[1];
    const float* W = (const float*)d_in[2];
    const float* b = (const float*)d_in[3];
    float* out = (float*)d_out;

    int N = in_sizes[0] / D;
    int E = in_sizes[1] / 2;

    char* ws = (char*)d_ws;
    float* dinv      = (float*)(ws + 0);
    int* cnt         = (int*)(ws + (512 << 10));
    int* rowstart    = (int*)(ws + (1024 << 10));
    int* cursor      = (int*)(ws + (1536 << 10));
    int* bsum        = (int*)(ws + (2048 << 10));
    int* boff        = (int*)(ws + (2048 << 10) + 4096);
    int* eidx        = (int*)(ws + (2056 << 10));             // E*4 = 2.44 MB
    unsigned short* h = (unsigned short*)(ws + (4608 << 10)); // N*128*2 = 24.4 MB
    unsigned int* h2 = (unsigned int*)h;

    hipMemsetAsync(cnt, 0, (size_t)N * 4, stream);

    count_k<<<((E + 3) / 4 + 255) / 256, 256, 0, stream>>>(ei + E, cnt, E);
    int nb = (N + 1023) / 1024;
    scan_a<<<nb, 256, 0, stream>>>(cnt, rowstart, bsum, dinv, N);
    scan_b<<<1, 128, 0, stream>>>(bsum, boff, nb, rowstart, N);
    scan_c<<<(N + 255) / 256, 256, 0, stream>>>(rowstart, boff, cursor, N);
    gemm_mfma<<<(N + 63) / 64, 256, 0, stream>>>(x, W, dinv, h, N);
    fill_k<<<(E + 255) / 256, 256, 0, stream>>>(ei, cursor, eidx, E);
    agg_k<<<(N + 3) / 4, 256, 0, stream>>>(h2, x, b, dinv, rowstart, eidx, out, N);
}

// Round 9
// 149.406 us; speedup vs baseline: 1.7414x; 1.0670x over previous
//
#include <hip/hip_runtime.h>

#define D 128

typedef __attribute__((ext_vector_type(8))) short short8;
typedef __attribute__((ext_vector_type(4))) float f32x4;

// ---------- bf16 helpers (manual, RNE) ----------
static __device__ __forceinline__ unsigned short f2bf(float f) {
    unsigned int u = __float_as_uint(f);
    u += 0x7fffu + ((u >> 16) & 1u);
    return (unsigned short)(u >> 16);
}
static __device__ __forceinline__ float bf_lo(unsigned int v) {
    return __uint_as_float(v << 16);
}
static __device__ __forceinline__ float bf_hi(unsigned int v) {
    return __uint_as_float(v & 0xffff0000u);
}

// ---------- MFMA GEMM: hs = (x @ W) * dinv[row], stored bf16 ----------
// Persistent: 768 blocks (3/CU), W staged ONCE per block, grid-stride tiles.
__global__ __launch_bounds__(256) void gemm_mfma(const float* __restrict__ x,
                                                 const float* __restrict__ W,
                                                 const float* __restrict__ dinv,
                                                 unsigned short* __restrict__ h,
                                                 int N, int ntiles) {
    __shared__ unsigned short Wt[D * D];       // transposed W, bf16, XOR-swizzled (32 KB)
    __shared__ unsigned short ost[4][16 * D];  // per-wave output stage (16 KB)

    int t = threadIdx.x;
    int w = t >> 6, l = t & 63;
    int mrow = l & 15, kgrp = l >> 4;

    // ---- stage Wt[c][k] = bf16(W[k][c]), swizzled: byte ^= (c&7)<<4 ----
    {
        const float4* Wv = (const float4*)W;
#pragma unroll
        for (int i = 0; i < 16; ++i) {
            int idx = i * 256 + t;       // 4096 float4 total
            int k = idx >> 5;            // W row
            int c0 = (idx & 31) * 4;     // W col
            float4 v = Wv[idx];
            float vv[4] = {v.x, v.y, v.z, v.w};
#pragma unroll
            for (int j = 0; j < 4; ++j) {
                int c = c0 + j;
                unsigned int B = (unsigned int)c * 256 + (unsigned int)k * 2;
                unsigned int sB = B ^ (((unsigned int)c & 7u) << 4);
                *(unsigned short*)((char*)Wt + sB) = f2bf(vv[j]);
            }
        }
    }
    __syncthreads();

    for (int tile = blockIdx.x; tile < ntiles; tile += gridDim.x) {
        int row0 = tile * 64 + w * 16;  // N % 16 == 0
        bool act = row0 < N;

        if (act) {
            short8 a[4];
#pragma unroll
            for (int kk = 0; kk < 4; ++kk) {
                const float* p = &x[(size_t)(row0 + mrow) * D + kk * 32 + kgrp * 8];
                float4 q0 = *(const float4*)p;
                float4 q1 = *(const float4*)(p + 4);
                short8 af;
                af[0] = (short)f2bf(q0.x); af[1] = (short)f2bf(q0.y);
                af[2] = (short)f2bf(q0.z); af[3] = (short)f2bf(q0.w);
                af[4] = (short)f2bf(q1.x); af[5] = (short)f2bf(q1.y);
                af[6] = (short)f2bf(q1.z); af[7] = (short)f2bf(q1.w);
                a[kk] = af;
            }
            f32x4 acc[8];
#pragma unroll
            for (int nt = 0; nt < 8; ++nt) {
                acc[nt] = (f32x4){0.f, 0.f, 0.f, 0.f};
#pragma unroll
                for (int kk = 0; kk < 4; ++kk) {
                    unsigned int c = nt * 16 + mrow;
                    unsigned int B = c * 256 + (unsigned int)(kk * 32 + kgrp * 8) * 2;
                    unsigned int sB = B ^ ((c & 7u) << 4);
                    short8 bf = *(const short8*)((char*)Wt + sB);
                    acc[nt] = __builtin_amdgcn_mfma_f32_16x16x32_bf16(a[kk], bf, acc[nt], 0, 0, 0);
                }
            }
            float dv[4];
#pragma unroll
            for (int j = 0; j < 4; ++j) dv[j] = dinv[row0 + kgrp * 4 + j];
#pragma unroll
            for (int nt = 0; nt < 8; ++nt)
#pragma unroll
                for (int j = 0; j < 4; ++j) {
                    int rr = kgrp * 4 + j;
                    ost[w][rr * D + nt * 16 + mrow] = f2bf(acc[nt][j] * dv[j]);
                }
        }
        __syncthreads();  // LDS stage -> readback ordering (all waves participate)
        if (act) {
            const uint4* os4 = (const uint4*)ost[w];
            uint4* H4 = (uint4*)h;
#pragma unroll
            for (int i2 = 0; i2 < 4; ++i2) {
                int e = i2 * 64 + l;
                H4[(size_t)row0 * 16 + e] = os4[e];
            }
        }
        __syncthreads();  // readback -> next-tile overwrite (WAR)
    }
}

// ---------- degree count over dst (vectorized) ----------
__global__ void count_k(const int* __restrict__ dst, int* __restrict__ cnt, int E) {
    int e = (blockIdx.x * blockDim.x + threadIdx.x) * 4;
    if (e + 3 < E) {
        int4 d = *(const int4*)&dst[e];
        atomicAdd(&cnt[d.x], 1);
        atomicAdd(&cnt[d.y], 1);
        atomicAdd(&cnt[d.z], 1);
        atomicAdd(&cnt[d.w], 1);
    } else {
        for (int q = e; q < E; ++q) atomicAdd(&cnt[dst[q]], 1);
    }
}

// ---------- scan phase A + fused dinv ----------
__global__ __launch_bounds__(256) void scan_a(const int* __restrict__ cnt,
                                              int* __restrict__ rowstart,
                                              int* __restrict__ bsum,
                                              float* __restrict__ dinv, int N) {
    __shared__ int sh[256];
    int t = threadIdx.x;
    int base = blockIdx.x * 1024 + t * 4;
    int v[4];
#pragma unroll
    for (int j = 0; j < 4; ++j) v[j] = (base + j < N) ? cnt[base + j] : 0;
#pragma unroll
    for (int j = 0; j < 4; ++j)
        if (base + j < N) dinv[base + j] = rsqrtf((float)v[j] + 1.0f);
    int ts = v[0] + v[1] + v[2] + v[3];
    sh[t] = ts;
    __syncthreads();
    for (int off = 1; off < 256; off <<= 1) {
        int u = (t >= off) ? sh[t - off] : 0;
        __syncthreads();
        sh[t] += u;
        __syncthreads();
    }
    int run = sh[t] - ts;
#pragma unroll
    for (int j = 0; j < 4; ++j) {
        if (base + j < N) rowstart[base + j] = run;
        run += v[j];
    }
    if (t == 255) bsum[blockIdx.x] = sh[255];
}

// ---------- scan B+C merged: every block locally scans bsum, finalizes ----------
__global__ __launch_bounds__(256) void scan_bc(int* __restrict__ rowstart,
                                               const int* __restrict__ bsum,
                                               int* __restrict__ cursor,
                                               int nb, int N) {
    __shared__ int sb[256];
    int t = threadIdx.x;
    sb[t] = (t < nb) ? bsum[t] : 0;
    __syncthreads();
    for (int off = 1; off < 256; off <<= 1) {
        int u = (t >= off) ? sb[t - off] : 0;
        __syncthreads();
        sb[t] += u;
        __syncthreads();
    }
    int boff = (blockIdx.x > 0) ? sb[blockIdx.x - 1] : 0;
    if (blockIdx.x == 0 && t == 0) rowstart[N] = sb[255];  // total == E

    int base = blockIdx.x * 1024 + t * 4;
#pragma unroll
    for (int j = 0; j < 4; ++j) {
        int i = base + j;
        if (i < N) {
            int r = rowstart[i] + boff;
            rowstart[i] = r;
            cursor[i] = r;
        }
    }
}

// ---------- fill CSR edge lists (src per dst), absolute cursor ----------
__global__ void fill_k(const int* __restrict__ ei, int* __restrict__ cursor,
                       int* __restrict__ eidx, int E) {
    int e = blockIdx.x * blockDim.x + threadIdx.x;
    if (e < E) {
        int s = ei[e];
        int d = ei[E + e];
        int p = atomicAdd(&cursor[d], 1);
        eidx[p] = s;
    }
}

// ---------- pull-mode aggregate + bias + relu + residual (fused) ----------
// 16-lane-group gather: lane l = (group g = l>>4, col = l&15). Group g owns
// edge k+g; lane loads uint4 (16 B = 8 bf16 cols) of that edge's h row ->
// ONE load instruction fetches 4 full rows (1 KB). Self-loop is a virtual
// edge (idxv = i on lanes >= deg). All shfls full-exec, uniform bounds.
__global__ __launch_bounds__(256) void agg_k(const unsigned int* __restrict__ h2,
                                             const float* __restrict__ x,
                                             const float* __restrict__ b,
                                             const float* __restrict__ dinv,
                                             const int* __restrict__ rowstart,
                                             const int* __restrict__ eidx,
                                             float* __restrict__ out, int N) {
    int w = threadIdx.x >> 6;
    int lane = threadIdx.x & 63;
    int grp = lane >> 4;
    int col = lane & 15;
    int i = blockIdx.x * 4 + w;
    if (i >= N) return;

    int rs = rowstart[i];
    int deg = rowstart[i + 1] - rs;  // wave-uniform
    float di = dinv[i];

    const uint4* H16 = (const uint4*)h2;

    // preload edge indices; lanes >= deg hold self (slot 'deg' = self-loop)
    int idxv = (lane < deg) ? eidx[rs + lane] : i;

    int nd = deg + 1;              // + self
    int dk = nd < 64 ? nd : 64;    // preloaded portion, wave-uniform

    float a0 = 0.f, a1 = 0.f, a2 = 0.f, a3 = 0.f;
    float a4 = 0.f, a5 = 0.f, a6 = 0.f, a7 = 0.f;

    for (int k = 0; k < dk; k += 4) {      // uniform cond; 4 edges/load-instr
        int sE = __shfl(idxv, k + grp, 64);  // full-exec (k+grp <= 63)
        if (k + grp < dk) {                  // predicated load only
            uint4 v = H16[(size_t)sE * 16 + col];
            a0 += bf_lo(v.x); a1 += bf_hi(v.x);
            a2 += bf_lo(v.y); a3 += bf_hi(v.y);
            a4 += bf_lo(v.z); a5 += bf_hi(v.z);
            a6 += bf_lo(v.w); a7 += bf_hi(v.w);
        }
    }
    for (int p = 64 + grp; p < nd; p += 4) {  // rare: deg >= 64 (no shfl)
        int sE = (p < deg) ? eidx[rs + p] : i;
        uint4 v = H16[(size_t)sE * 16 + col];
        a0 += bf_lo(v.x); a1 += bf_hi(v.x);
        a2 += bf_lo(v.y); a3 += bf_hi(v.y);
        a4 += bf_lo(v.z); a5 += bf_hi(v.z);
        a6 += bf_lo(v.w); a7 += bf_hi(v.w);
    }

    // combine the 4 groups (all lanes active)
    a0 += __shfl_xor(a0, 16, 64); a1 += __shfl_xor(a1, 16, 64);
    a2 += __shfl_xor(a2, 16, 64); a3 += __shfl_xor(a3, 16, 64);
    a4 += __shfl_xor(a4, 16, 64); a5 += __shfl_xor(a5, 16, 64);
    a6 += __shfl_xor(a6, 16, 64); a7 += __shfl_xor(a7, 16, 64);
    a0 += __shfl_xor(a0, 32, 64); a1 += __shfl_xor(a1, 32, 64);
    a2 += __shfl_xor(a2, 32, 64); a3 += __shfl_xor(a3, 32, 64);
    a4 += __shfl_xor(a4, 32, 64); a5 += __shfl_xor(a5, 32, 64);
    a6 += __shfl_xor(a6, 32, 64); a7 += __shfl_xor(a7, 32, 64);

    if (grp == 0) {  // lanes 0..15 write cols col*8 .. col*8+7
        size_t base = (size_t)i * D + col * 8;
        float4 b0 = *(const float4*)&b[col * 8];
        float4 b1 = *(const float4*)&b[col * 8 + 4];
        const f32x4* px0 = (const f32x4*)&x[base];
        const f32x4* px1 = (const f32x4*)&x[base + 4];
        f32x4 x0 = __builtin_nontemporal_load(px0);
        f32x4 x1 = __builtin_nontemporal_load(px1);
        f32x4 o0, o1;
        o0.x = x0.x + fmaxf(a0 * di + b0.x, 0.f);
        o0.y = x0.y + fmaxf(a1 * di + b0.y, 0.f);
        o0.z = x0.z + fmaxf(a2 * di + b0.z, 0.f);
        o0.w = x0.w + fmaxf(a3 * di + b0.w, 0.f);
        o1.x = x1.x + fmaxf(a4 * di + b1.x, 0.f);
        o1.y = x1.y + fmaxf(a5 * di + b1.y, 0.f);
        o1.z = x1.z + fmaxf(a6 * di + b1.z, 0.f);
        o1.w = x1.w + fmaxf(a7 * di + b1.w, 0.f);
        __builtin_nontemporal_store(o0, (f32x4*)&out[base]);
        __builtin_nontemporal_store(o1, (f32x4*)&out[base + 4]);
    }
}

extern "C" void kernel_launch(void* const* d_in, const int* in_sizes, int n_in,
                              void* d_out, int out_size, void* d_ws, size_t ws_size,
                              hipStream_t stream) {
    const float* x = (const float*)d_in[0];
    const int* ei = (const int*)d_in[1];
    const float* W = (const float*)d_in[2];
    const float* b = (const float*)d_in[3];
    float* out = (float*)d_out;

    int N = in_sizes[0] / D;
    int E = in_sizes[1] / 2;

    char* ws = (char*)d_ws;
    float* dinv      = (float*)(ws + 0);
    int* cnt         = (int*)(ws + (512 << 10));
    int* rowstart    = (int*)(ws + (1024 << 10));
    int* cursor      = (int*)(ws + (1536 << 10));
    int* bsum        = (int*)(ws + (2048 << 10));
    int* eidx        = (int*)(ws + (2056 << 10));             // E*4 = 2.44 MB
    unsigned short* h = (unsigned short*)(ws + (4608 << 10)); // N*128*2 = 24.4 MB
    unsigned int* h2 = (unsigned int*)h;

    hipMemsetAsync(cnt, 0, (size_t)N * 4, stream);

    count_k<<<((E + 3) / 4 + 255) / 256, 256, 0, stream>>>(ei + E, cnt, E);
    int nb = (N + 1023) / 1024;
    scan_a<<<nb, 256, 0, stream>>>(cnt, rowstart, bsum, dinv, N);
    scan_bc<<<nb, 256, 0, stream>>>(rowstart, bsum, cursor, nb, N);
    int ntiles = (N + 63) / 64;
    int ngrid = ntiles < 768 ? ntiles : 768;
    gemm_mfma<<<ngrid, 256, 0, stream>>>(x, W, dinv, h, N, ntiles);
    fill_k<<<(E + 255) / 256, 256, 0, stream>>>(ei, cursor, eidx, E);
    agg_k<<<(N + 3) / 4, 256, 0, stream>>>(h2, x, b, dinv, rowstart, eidx, out, N);
}

// Round 10
// 143.094 us; speedup vs baseline: 1.8182x; 1.0441x over previous
//
#include <hip/hip_runtime.h>

#define D 128

typedef __attribute__((ext_vector_type(8))) short short8;
typedef __attribute__((ext_vector_type(4))) float f32x4;

// ---------- bf16 helpers (manual, RNE) ----------
static __device__ __forceinline__ unsigned short f2bf(float f) {
    unsigned int u = __float_as_uint(f);
    u += 0x7fffu + ((u >> 16) & 1u);
    return (unsigned short)(u >> 16);
}
static __device__ __forceinline__ float bf_lo(unsigned int v) {
    return __uint_as_float(v << 16);
}
static __device__ __forceinline__ float bf_hi(unsigned int v) {
    return __uint_as_float(v & 0xffff0000u);
}

// ---------- MFMA GEMM: hs = (x @ W) * dinv[row], stored bf16 ----------
// Persistent: 768 blocks (3/CU), W staged ONCE per block, grid-stride tiles.
__global__ __launch_bounds__(256) void gemm_mfma(const float* __restrict__ x,
                                                 const float* __restrict__ W,
                                                 const float* __restrict__ dinv,
                                                 unsigned short* __restrict__ h,
                                                 int N, int ntiles) {
    __shared__ unsigned short Wt[D * D];       // transposed W, bf16, XOR-swizzled (32 KB)
    __shared__ unsigned short ost[4][16 * D];  // per-wave output stage (16 KB)

    int t = threadIdx.x;
    int w = t >> 6, l = t & 63;
    int mrow = l & 15, kgrp = l >> 4;

    // ---- stage Wt[c][k] = bf16(W[k][c]), swizzled: byte ^= (c&7)<<4 ----
    {
        const float4* Wv = (const float4*)W;
#pragma unroll
        for (int i = 0; i < 16; ++i) {
            int idx = i * 256 + t;       // 4096 float4 total
            int k = idx >> 5;            // W row
            int c0 = (idx & 31) * 4;     // W col
            float4 v = Wv[idx];
            float vv[4] = {v.x, v.y, v.z, v.w};
#pragma unroll
            for (int j = 0; j < 4; ++j) {
                int c = c0 + j;
                unsigned int B = (unsigned int)c * 256 + (unsigned int)k * 2;
                unsigned int sB = B ^ (((unsigned int)c & 7u) << 4);
                *(unsigned short*)((char*)Wt + sB) = f2bf(vv[j]);
            }
        }
    }
    __syncthreads();

    for (int tile = blockIdx.x; tile < ntiles; tile += gridDim.x) {
        int row0 = tile * 64 + w * 16;  // N % 16 == 0
        bool act = row0 < N;

        if (act) {
            short8 a[4];
#pragma unroll
            for (int kk = 0; kk < 4; ++kk) {
                const float* p = &x[(size_t)(row0 + mrow) * D + kk * 32 + kgrp * 8];
                float4 q0 = *(const float4*)p;
                float4 q1 = *(const float4*)(p + 4);
                short8 af;
                af[0] = (short)f2bf(q0.x); af[1] = (short)f2bf(q0.y);
                af[2] = (short)f2bf(q0.z); af[3] = (short)f2bf(q0.w);
                af[4] = (short)f2bf(q1.x); af[5] = (short)f2bf(q1.y);
                af[6] = (short)f2bf(q1.z); af[7] = (short)f2bf(q1.w);
                a[kk] = af;
            }
            f32x4 acc[8];
#pragma unroll
            for (int nt = 0; nt < 8; ++nt) {
                acc[nt] = (f32x4){0.f, 0.f, 0.f, 0.f};
#pragma unroll
                for (int kk = 0; kk < 4; ++kk) {
                    unsigned int c = nt * 16 + mrow;
                    unsigned int B = c * 256 + (unsigned int)(kk * 32 + kgrp * 8) * 2;
                    unsigned int sB = B ^ ((c & 7u) << 4);
                    short8 bf = *(const short8*)((char*)Wt + sB);
                    acc[nt] = __builtin_amdgcn_mfma_f32_16x16x32_bf16(a[kk], bf, acc[nt], 0, 0, 0);
                }
            }
            float dv[4];
#pragma unroll
            for (int j = 0; j < 4; ++j) dv[j] = dinv[row0 + kgrp * 4 + j];
#pragma unroll
            for (int nt = 0; nt < 8; ++nt)
#pragma unroll
                for (int j = 0; j < 4; ++j) {
                    int rr = kgrp * 4 + j;
                    ost[w][rr * D + nt * 16 + mrow] = f2bf(acc[nt][j] * dv[j]);
                }
        }
        __syncthreads();  // LDS stage -> readback ordering
        if (act) {
            const uint4* os4 = (const uint4*)ost[w];
            uint4* H4 = (uint4*)h;
#pragma unroll
            for (int i2 = 0; i2 < 4; ++i2) {
                int e = i2 * 64 + l;
                H4[(size_t)row0 * 16 + e] = os4[e];
            }
        }
        __syncthreads();  // readback -> next-tile overwrite (WAR)
    }
}

// ---------- degree count over dst (vectorized) ----------
__global__ void count_k(const int* __restrict__ dst, int* __restrict__ cnt, int E) {
    int e = (blockIdx.x * blockDim.x + threadIdx.x) * 4;
    if (e + 3 < E) {
        int4 d = *(const int4*)&dst[e];
        atomicAdd(&cnt[d.x], 1);
        atomicAdd(&cnt[d.y], 1);
        atomicAdd(&cnt[d.z], 1);
        atomicAdd(&cnt[d.w], 1);
    } else {
        for (int q = e; q < E; ++q) atomicAdd(&cnt[dst[q]], 1);
    }
}

// ---------- scan phase A + fused dinv ----------
__global__ __launch_bounds__(256) void scan_a(const int* __restrict__ cnt,
                                              int* __restrict__ rowstart,
                                              int* __restrict__ bsum,
                                              float* __restrict__ dinv, int N) {
    __shared__ int sh[256];
    int t = threadIdx.x;
    int base = blockIdx.x * 1024 + t * 4;
    int v[4];
#pragma unroll
    for (int j = 0; j < 4; ++j) v[j] = (base + j < N) ? cnt[base + j] : 0;
#pragma unroll
    for (int j = 0; j < 4; ++j)
        if (base + j < N) dinv[base + j] = rsqrtf((float)v[j] + 1.0f);
    int ts = v[0] + v[1] + v[2] + v[3];
    sh[t] = ts;
    __syncthreads();
    for (int off = 1; off < 256; off <<= 1) {
        int u = (t >= off) ? sh[t - off] : 0;
        __syncthreads();
        sh[t] += u;
        __syncthreads();
    }
    int run = sh[t] - ts;
#pragma unroll
    for (int j = 0; j < 4; ++j) {
        if (base + j < N) rowstart[base + j] = run;
        run += v[j];
    }
    if (t == 255) bsum[blockIdx.x] = sh[255];
}

// ---------- scan B+C merged ----------
__global__ __launch_bounds__(256) void scan_bc(int* __restrict__ rowstart,
                                               const int* __restrict__ bsum,
                                               int* __restrict__ cursor,
                                               int nb, int N) {
    __shared__ int sb[256];
    int t = threadIdx.x;
    sb[t] = (t < nb) ? bsum[t] : 0;
    __syncthreads();
    for (int off = 1; off < 256; off <<= 1) {
        int u = (t >= off) ? sb[t - off] : 0;
        __syncthreads();
        sb[t] += u;
        __syncthreads();
    }
    int boff = (blockIdx.x > 0) ? sb[blockIdx.x - 1] : 0;
    if (blockIdx.x == 0 && t == 0) rowstart[N] = sb[255];  // total == E

    int base = blockIdx.x * 1024 + t * 4;
#pragma unroll
    for (int j = 0; j < 4; ++j) {
        int i = base + j;
        if (i < N) {
            int r = rowstart[i] + boff;
            rowstart[i] = r;
            cursor[i] = r;
        }
    }
}

// ---------- fill CSR edge lists (src per dst), absolute cursor ----------
__global__ void fill_k(const int* __restrict__ ei, int* __restrict__ cursor,
                       int* __restrict__ eidx, int E) {
    int e = blockIdx.x * blockDim.x + threadIdx.x;
    if (e < E) {
        int s = ei[e];
        int d = ei[E + e];
        int p = atomicAdd(&cursor[d], 1);
        eidx[p] = s;
    }
}

// ---------- pull-mode aggregate + bias + relu + residual (fused) ----------
// TWO nodes per wave: half hf = lane>>5 owns node base+hf. Within a half:
// grp2 = parity group (16 lanes), col = lane&15 -> uint4 (8 bf16 cols).
// Each round issues 2 UNCONDITIONAL gathers per chain (every idxv slot is a
// valid node: slots >= deg hold self) -> 4 loads in flight per wave; only the
// accumulate is predicated. Loop bound mx is wave-uniform (max of halves'
// dk via shfl_xor) so every __shfl runs full-exec (round-3/4 lesson).
__global__ __launch_bounds__(256) void agg_k(const unsigned int* __restrict__ h2,
                                             const float* __restrict__ x,
                                             const float* __restrict__ b,
                                             const float* __restrict__ dinv,
                                             const int* __restrict__ rowstart,
                                             const int* __restrict__ eidx,
                                             float* __restrict__ out, int N) {
    int w = threadIdx.x >> 6;
    int lane = threadIdx.x & 63;
    int hf = lane >> 5;
    int sl = lane & 31;
    int grp2 = sl >> 4;
    int col = lane & 15;
    int base = (blockIdx.x * 4 + w) * 2;
    if (base >= N) return;
    int i = base + hf;
    if (i >= N) i = N - 1;  // N odd tail: both halves compute node N-1 (benign dup)

    int rs = rowstart[i];
    int deg = rowstart[i + 1] - rs;  // uniform within half
    float di = dinv[i];

    const uint4* H16 = (const uint4*)h2;

    // preload up to 32 edges for this half; slots >= deg hold self (valid!)
    int idxv = (sl < deg) ? eidx[rs + sl] : i;

    int nd = deg + 1;                 // + self-loop
    int dk = nd < 32 ? nd : 32;       // preloaded portion, uniform within half
    int dko = __shfl_xor(dk, 32, 64); // other half's dk (full exec)
    int mx = dk > dko ? dk : dko;     // wave-uniform loop bound

    float a0 = 0.f, a1 = 0.f, a2 = 0.f, a3 = 0.f;
    float a4 = 0.f, a5 = 0.f, a6 = 0.f, a7 = 0.f;

    int hb = hf << 5;
    int k = 0;
    for (; k + 4 <= mx; k += 4) {  // wave-uniform; 4 edges per half per iter
        int s0 = __shfl(idxv, hb + k + grp2, 64);
        int s1 = __shfl(idxv, hb + k + 2 + grp2, 64);
        uint4 v0 = H16[(size_t)s0 * 16 + col];  // unconditional: always valid row
        uint4 v1 = H16[(size_t)s1 * 16 + col];
        if (k + grp2 < dk) {
            a0 += bf_lo(v0.x); a1 += bf_hi(v0.x);
            a2 += bf_lo(v0.y); a3 += bf_hi(v0.y);
            a4 += bf_lo(v0.z); a5 += bf_hi(v0.z);
            a6 += bf_lo(v0.w); a7 += bf_hi(v0.w);
        }
        if (k + 2 + grp2 < dk) {
            a0 += bf_lo(v1.x); a1 += bf_hi(v1.x);
            a2 += bf_lo(v1.y); a3 += bf_hi(v1.y);
            a4 += bf_lo(v1.z); a5 += bf_hi(v1.z);
            a6 += bf_lo(v1.w); a7 += bf_hi(v1.w);
        }
    }
    if (k < mx) {  // wave-uniform tail (1..3 slots); max source index k+3 <= 31
        int s0 = __shfl(idxv, hb + k + grp2, 64);
        int s1 = __shfl(idxv, hb + k + 2 + grp2, 64);
        uint4 v0 = H16[(size_t)s0 * 16 + col];
        uint4 v1 = H16[(size_t)s1 * 16 + col];
        if (k + grp2 < dk) {
            a0 += bf_lo(v0.x); a1 += bf_hi(v0.x);
            a2 += bf_lo(v0.y); a3 += bf_hi(v0.y);
            a4 += bf_lo(v0.z); a5 += bf_hi(v0.z);
            a6 += bf_lo(v0.w); a7 += bf_hi(v0.w);
        }
        if (k + 2 + grp2 < dk) {
            a0 += bf_lo(v1.x); a1 += bf_hi(v1.x);
            a2 += bf_lo(v1.y); a3 += bf_hi(v1.y);
            a4 += bf_lo(v1.z); a5 += bf_hi(v1.z);
            a6 += bf_lo(v1.w); a7 += bf_hi(v1.w);
        }
    }
    for (int p = 32 + grp2; p < nd; p += 2) {  // rare: deg >= 32 (no shfl here)
        int sE = (p < deg) ? eidx[rs + p] : i;
        uint4 v = H16[(size_t)sE * 16 + col];
        a0 += bf_lo(v.x); a1 += bf_hi(v.x);
        a2 += bf_lo(v.y); a3 += bf_hi(v.y);
        a4 += bf_lo(v.z); a5 += bf_hi(v.z);
        a6 += bf_lo(v.w); a7 += bf_hi(v.w);
    }

    // combine the grp2 pair within each half (full exec)
    a0 += __shfl_xor(a0, 16, 64); a1 += __shfl_xor(a1, 16, 64);
    a2 += __shfl_xor(a2, 16, 64); a3 += __shfl_xor(a3, 16, 64);
    a4 += __shfl_xor(a4, 16, 64); a5 += __shfl_xor(a5, 16, 64);
    a6 += __shfl_xor(a6, 16, 64); a7 += __shfl_xor(a7, 16, 64);

    if (grp2 == 0 && (base + hf) < N) {  // 16 lanes per half write their node
        size_t ob = (size_t)i * D + col * 8;
        float4 b0 = *(const float4*)&b[col * 8];
        float4 b1 = *(const float4*)&b[col * 8 + 4];
        const f32x4* px0 = (const f32x4*)&x[ob];
        const f32x4* px1 = (const f32x4*)&x[ob + 4];
        f32x4 x0 = __builtin_nontemporal_load(px0);
        f32x4 x1 = __builtin_nontemporal_load(px1);
        f32x4 o0, o1;
        o0.x = x0.x + fmaxf(a0 * di + b0.x, 0.f);
        o0.y = x0.y + fmaxf(a1 * di + b0.y, 0.f);
        o0.z = x0.z + fmaxf(a2 * di + b0.z, 0.f);
        o0.w = x0.w + fmaxf(a3 * di + b0.w, 0.f);
        o1.x = x1.x + fmaxf(a4 * di + b1.x, 0.f);
        o1.y = x1.y + fmaxf(a5 * di + b1.y, 0.f);
        o1.z = x1.z + fmaxf(a6 * di + b1.z, 0.f);
        o1.w = x1.w + fmaxf(a7 * di + b1.w, 0.f);
        __builtin_nontemporal_store(o0, (f32x4*)&out[ob]);
        __builtin_nontemporal_store(o1, (f32x4*)&out[ob + 4]);
    }
}

extern "C" void kernel_launch(void* const* d_in, const int* in_sizes, int n_in,
                              void* d_out, int out_size, void* d_ws, size_t ws_size,
                              hipStream_t stream) {
    const float* x = (const float*)d_in[0];
    const int* ei = (const int*)d_in[1];
    const float* W = (const float*)d_in[2];
    const float* b = (const float*)d_in[3];
    float* out = (float*)d_out;

    int N = in_sizes[0] / D;
    int E = in_sizes[1] / 2;

    char* ws = (char*)d_ws;
    float* dinv      = (float*)(ws + 0);
    int* cnt         = (int*)(ws + (512 << 10));
    int* rowstart    = (int*)(ws + (1024 << 10));
    int* cursor      = (int*)(ws + (1536 << 10));
    int* bsum        = (int*)(ws + (2048 << 10));
    int* eidx        = (int*)(ws + (2056 << 10));             // E*4 = 2.44 MB
    unsigned short* h = (unsigned short*)(ws + (4608 << 10)); // N*128*2 = 24.4 MB
    unsigned int* h2 = (unsigned int*)h;

    hipMemsetAsync(cnt, 0, (size_t)N * 4, stream);

    count_k<<<((E + 3) / 4 + 255) / 256, 256, 0, stream>>>(ei + E, cnt, E);
    int nb = (N + 1023) / 1024;
    scan_a<<<nb, 256, 0, stream>>>(cnt, rowstart, bsum, dinv, N);
    scan_bc<<<nb, 256, 0, stream>>>(rowstart, bsum, cursor, nb, N);
    int ntiles = (N + 63) / 64;
    int ngrid = ntiles < 768 ? ntiles : 768;
    gemm_mfma<<<ngrid, 256, 0, stream>>>(x, W, dinv, h, N, ntiles);
    fill_k<<<(E + 255) / 256, 256, 0, stream>>>(ei, cursor, eidx, E);
    agg_k<<<(N + 7) / 8, 256, 0, stream>>>(h2, x, b, dinv, rowstart, eidx, out, N);
}

// Round 11
// 142.162 us; speedup vs baseline: 1.8302x; 1.0066x over previous
//
#include <hip/hip_runtime.h>

#define D 128

typedef __attribute__((ext_vector_type(8))) short short8;
typedef __attribute__((ext_vector_type(4))) float f32x4;

// ---------- bf16 helpers (manual, RNE) ----------
static __device__ __forceinline__ unsigned short f2bf(float f) {
    unsigned int u = __float_as_uint(f);
    u += 0x7fffu + ((u >> 16) & 1u);
    return (unsigned short)(u >> 16);
}
static __device__ __forceinline__ float bf_lo(unsigned int v) {
    return __uint_as_float(v << 16);
}
static __device__ __forceinline__ float bf_hi(unsigned int v) {
    return __uint_as_float(v & 0xffff0000u);
}

// ---------- MFMA GEMM: hs = (x @ W) * dinv[row], stored bf16 ----------
// Persistent: 768 blocks (3/CU), W staged ONCE per block, grid-stride tiles.
__global__ __launch_bounds__(256) void gemm_mfma(const float* __restrict__ x,
                                                 const float* __restrict__ W,
                                                 const float* __restrict__ dinv,
                                                 unsigned short* __restrict__ h,
                                                 int N, int ntiles) {
    __shared__ unsigned short Wt[D * D];       // transposed W, bf16, XOR-swizzled (32 KB)
    __shared__ unsigned short ost[4][16 * D];  // per-wave output stage (16 KB)

    int t = threadIdx.x;
    int w = t >> 6, l = t & 63;
    int mrow = l & 15, kgrp = l >> 4;

    // ---- stage Wt[c][k] = bf16(W[k][c]), swizzled: byte ^= (c&7)<<4 ----
    {
        const float4* Wv = (const float4*)W;
#pragma unroll
        for (int i = 0; i < 16; ++i) {
            int idx = i * 256 + t;       // 4096 float4 total
            int k = idx >> 5;            // W row
            int c0 = (idx & 31) * 4;     // W col
            float4 v = Wv[idx];
            float vv[4] = {v.x, v.y, v.z, v.w};
#pragma unroll
            for (int j = 0; j < 4; ++j) {
                int c = c0 + j;
                unsigned int B = (unsigned int)c * 256 + (unsigned int)k * 2;
                unsigned int sB = B ^ (((unsigned int)c & 7u) << 4);
                *(unsigned short*)((char*)Wt + sB) = f2bf(vv[j]);
            }
        }
    }
    __syncthreads();

    for (int tile = blockIdx.x; tile < ntiles; tile += gridDim.x) {
        int row0 = tile * 64 + w * 16;  // N % 16 == 0
        bool act = row0 < N;

        if (act) {
            short8 a[4];
#pragma unroll
            for (int kk = 0; kk < 4; ++kk) {
                const float* p = &x[(size_t)(row0 + mrow) * D + kk * 32 + kgrp * 8];
                float4 q0 = *(const float4*)p;
                float4 q1 = *(const float4*)(p + 4);
                short8 af;
                af[0] = (short)f2bf(q0.x); af[1] = (short)f2bf(q0.y);
                af[2] = (short)f2bf(q0.z); af[3] = (short)f2bf(q0.w);
                af[4] = (short)f2bf(q1.x); af[5] = (short)f2bf(q1.y);
                af[6] = (short)f2bf(q1.z); af[7] = (short)f2bf(q1.w);
                a[kk] = af;
            }
            f32x4 acc[8];
#pragma unroll
            for (int nt = 0; nt < 8; ++nt) {
                acc[nt] = (f32x4){0.f, 0.f, 0.f, 0.f};
#pragma unroll
                for (int kk = 0; kk < 4; ++kk) {
                    unsigned int c = nt * 16 + mrow;
                    unsigned int B = c * 256 + (unsigned int)(kk * 32 + kgrp * 8) * 2;
                    unsigned int sB = B ^ ((c & 7u) << 4);
                    short8 bf = *(const short8*)((char*)Wt + sB);
                    acc[nt] = __builtin_amdgcn_mfma_f32_16x16x32_bf16(a[kk], bf, acc[nt], 0, 0, 0);
                }
            }
            float dv[4];
#pragma unroll
            for (int j = 0; j < 4; ++j) dv[j] = dinv[row0 + kgrp * 4 + j];
#pragma unroll
            for (int nt = 0; nt < 8; ++nt)
#pragma unroll
                for (int j = 0; j < 4; ++j) {
                    int rr = kgrp * 4 + j;
                    ost[w][rr * D + nt * 16 + mrow] = f2bf(acc[nt][j] * dv[j]);
                }
        }
        __syncthreads();  // LDS stage -> readback ordering
        if (act) {
            const uint4* os4 = (const uint4*)ost[w];
            uint4* H4 = (uint4*)h;
#pragma unroll
            for (int i2 = 0; i2 < 4; ++i2) {
                int e = i2 * 64 + l;
                H4[(size_t)row0 * 16 + e] = os4[e];
            }
        }
        __syncthreads();  // readback -> next-tile overwrite (WAR)
    }
}

// ---------- degree count over dst (vectorized) ----------
__global__ void count_k(const int* __restrict__ dst, int* __restrict__ cnt, int E) {
    int e = (blockIdx.x * blockDim.x + threadIdx.x) * 4;
    if (e + 3 < E) {
        int4 d = *(const int4*)&dst[e];
        atomicAdd(&cnt[d.x], 1);
        atomicAdd(&cnt[d.y], 1);
        atomicAdd(&cnt[d.z], 1);
        atomicAdd(&cnt[d.w], 1);
    } else {
        for (int q = e; q < E; ++q) atomicAdd(&cnt[dst[q]], 1);
    }
}

// ---------- scan phase A + fused dinv ----------
__global__ __launch_bounds__(256) void scan_a(const int* __restrict__ cnt,
                                              int* __restrict__ rowstart,
                                              int* __restrict__ bsum,
                                              float* __restrict__ dinv, int N) {
    __shared__ int sh[256];
    int t = threadIdx.x;
    int base = blockIdx.x * 1024 + t * 4;
    int v[4];
#pragma unroll
    for (int j = 0; j < 4; ++j) v[j] = (base + j < N) ? cnt[base + j] : 0;
#pragma unroll
    for (int j = 0; j < 4; ++j)
        if (base + j < N) dinv[base + j] = rsqrtf((float)v[j] + 1.0f);
    int ts = v[0] + v[1] + v[2] + v[3];
    sh[t] = ts;
    __syncthreads();
    for (int off = 1; off < 256; off <<= 1) {
        int u = (t >= off) ? sh[t - off] : 0;
        __syncthreads();
        sh[t] += u;
        __syncthreads();
    }
    int run = sh[t] - ts;
#pragma unroll
    for (int j = 0; j < 4; ++j) {
        if (base + j < N) rowstart[base + j] = run;
        run += v[j];
    }
    if (t == 255) bsum[blockIdx.x] = sh[255];
}

// ---------- scan B+C merged ----------
__global__ __launch_bounds__(256) void scan_bc(int* __restrict__ rowstart,
                                               const int* __restrict__ bsum,
                                               int* __restrict__ cursor,
                                               int nb, int N) {
    __shared__ int sb[256];
    int t = threadIdx.x;
    sb[t] = (t < nb) ? bsum[t] : 0;
    __syncthreads();
    for (int off = 1; off < 256; off <<= 1) {
        int u = (t >= off) ? sb[t - off] : 0;
        __syncthreads();
        sb[t] += u;
        __syncthreads();
    }
    int boff = (blockIdx.x > 0) ? sb[blockIdx.x - 1] : 0;
    if (blockIdx.x == 0 && t == 0) rowstart[N] = sb[255];  // total == E

    int base = blockIdx.x * 1024 + t * 4;
#pragma unroll
    for (int j = 0; j < 4; ++j) {
        int i = base + j;
        if (i < N) {
            int r = rowstart[i] + boff;
            rowstart[i] = r;
            cursor[i] = r;
        }
    }
}

// ---------- fill CSR edge lists (src per dst), absolute cursor, 2 edges/thread ----------
__global__ void fill_k(const int* __restrict__ ei, int* __restrict__ cursor,
                       int* __restrict__ eidx, int E) {
    int e = (blockIdx.x * blockDim.x + threadIdx.x) * 2;
    if (e + 1 < E) {
        int2 s = *(const int2*)&ei[e];
        int2 d = *(const int2*)&ei[E + e];
        int p0 = atomicAdd(&cursor[d.x], 1);
        eidx[p0] = s.x;
        int p1 = atomicAdd(&cursor[d.y], 1);
        eidx[p1] = s.y;
    } else if (e < E) {
        int p = atomicAdd(&cursor[ei[E + e]], 1);
        eidx[p] = ei[e];
    }
}

// ---------- pull-mode aggregate + bias + relu + residual (fused) ----------
// FOUR nodes per wave: 16-lane group g owns node. Lane col = lane&15 owns
// cols [8col, 8col+8) via uint4 (one load instr = full 256B row per group).
// Edge indices read DIRECTLY by all 16 lanes from eidx[rs+k] (same address
// -> broadcast; the node's eidx segment is 1-2 cache lines, L1-hot). NO
// cross-lane ops anywhere -> divergence between groups is safe. No final
// reduction: each lane owns its columns end-to-end. Unroll 4 -> 4
// independent eidx->gather chains per group, 16 gathers in flight per wave.
__global__ __launch_bounds__(256) void agg_k(const unsigned int* __restrict__ h2,
                                             const float* __restrict__ x,
                                             const float* __restrict__ b,
                                             const float* __restrict__ dinv,
                                             const int* __restrict__ rowstart,
                                             const int* __restrict__ eidx,
                                             float* __restrict__ out, int N) {
    int w = threadIdx.x >> 6;
    int lane = threadIdx.x & 63;
    int g = lane >> 4;
    int col = lane & 15;
    int i0 = (blockIdx.x * 4 + w) * 4 + g;
    bool valid = i0 < N;
    int i = valid ? i0 : N - 1;   // clamp; clamped groups compute but don't store

    int rs = rowstart[i];
    int deg = rowstart[i + 1] - rs;  // uniform within group
    float di = dinv[i];

    const uint4* H16 = (const uint4*)h2;

    float a0, a1, a2, a3, a4, a5, a6, a7;
    {   // self-loop row (always valid)
        uint4 sv = H16[(size_t)i * 16 + col];
        a0 = bf_lo(sv.x); a1 = bf_hi(sv.x);
        a2 = bf_lo(sv.y); a3 = bf_hi(sv.y);
        a4 = bf_lo(sv.z); a5 = bf_hi(sv.z);
        a6 = bf_lo(sv.w); a7 = bf_hi(sv.w);
    }

    int k = 0;
    for (; k + 4 <= deg; k += 4) {  // 4 independent eidx->gather chains
        int s0 = eidx[rs + k];
        int s1 = eidx[rs + k + 1];
        int s2 = eidx[rs + k + 2];
        int s3 = eidx[rs + k + 3];
        uint4 v0 = H16[(size_t)s0 * 16 + col];
        uint4 v1 = H16[(size_t)s1 * 16 + col];
        uint4 v2 = H16[(size_t)s2 * 16 + col];
        uint4 v3 = H16[(size_t)s3 * 16 + col];
        a0 += (bf_lo(v0.x) + bf_lo(v1.x)) + (bf_lo(v2.x) + bf_lo(v3.x));
        a1 += (bf_hi(v0.x) + bf_hi(v1.x)) + (bf_hi(v2.x) + bf_hi(v3.x));
        a2 += (bf_lo(v0.y) + bf_lo(v1.y)) + (bf_lo(v2.y) + bf_lo(v3.y));
        a3 += (bf_hi(v0.y) + bf_hi(v1.y)) + (bf_hi(v2.y) + bf_hi(v3.y));
        a4 += (bf_lo(v0.z) + bf_lo(v1.z)) + (bf_lo(v2.z) + bf_lo(v3.z));
        a5 += (bf_hi(v0.z) + bf_hi(v1.z)) + (bf_hi(v2.z) + bf_hi(v3.z));
        a6 += (bf_lo(v0.w) + bf_lo(v1.w)) + (bf_lo(v2.w) + bf_lo(v3.w));
        a7 += (bf_hi(v0.w) + bf_hi(v1.w)) + (bf_hi(v2.w) + bf_hi(v3.w));
    }
    for (; k < deg; ++k) {
        int s = eidx[rs + k];
        uint4 v = H16[(size_t)s * 16 + col];
        a0 += bf_lo(v.x); a1 += bf_hi(v.x);
        a2 += bf_lo(v.y); a3 += bf_hi(v.y);
        a4 += bf_lo(v.z); a5 += bf_hi(v.z);
        a6 += bf_lo(v.w); a7 += bf_hi(v.w);
    }

    if (valid) {  // all 64 lanes store: 4 rows per wave, 32B per lane
        size_t ob = (size_t)i * D + col * 8;
        float4 b0 = *(const float4*)&b[col * 8];
        float4 b1 = *(const float4*)&b[col * 8 + 4];
        const f32x4* px0 = (const f32x4*)&x[ob];
        const f32x4* px1 = (const f32x4*)&x[ob + 4];
        f32x4 x0 = __builtin_nontemporal_load(px0);
        f32x4 x1 = __builtin_nontemporal_load(px1);
        f32x4 o0, o1;
        o0.x = x0.x + fmaxf(a0 * di + b0.x, 0.f);
        o0.y = x0.y + fmaxf(a1 * di + b0.y, 0.f);
        o0.z = x0.z + fmaxf(a2 * di + b0.z, 0.f);
        o0.w = x0.w + fmaxf(a3 * di + b0.w, 0.f);
        o1.x = x1.x + fmaxf(a4 * di + b1.x, 0.f);
        o1.y = x1.y + fmaxf(a5 * di + b1.y, 0.f);
        o1.z = x1.z + fmaxf(a6 * di + b1.z, 0.f);
        o1.w = x1.w + fmaxf(a7 * di + b1.w, 0.f);
        __builtin_nontemporal_store(o0, (f32x4*)&out[ob]);
        __builtin_nontemporal_store(o1, (f32x4*)&out[ob + 4]);
    }
}

extern "C" void kernel_launch(void* const* d_in, const int* in_sizes, int n_in,
                              void* d_out, int out_size, void* d_ws, size_t ws_size,
                              hipStream_t stream) {
    const float* x = (const float*)d_in[0];
    const int* ei = (const int*)d_in[1];
    const float* W = (const float*)d_in[2];
    const float* b = (const float*)d_in[3];
    float* out = (float*)d_out;

    int N = in_sizes[0] / D;
    int E = in_sizes[1] / 2;

    char* ws = (char*)d_ws;
    float* dinv      = (float*)(ws + 0);
    int* cnt         = (int*)(ws + (512 << 10));
    int* rowstart    = (int*)(ws + (1024 << 10));
    int* cursor      = (int*)(ws + (1536 << 10));
    int* bsum        = (int*)(ws + (2048 << 10));
    int* eidx        = (int*)(ws + (2056 << 10));             // E*4 = 2.44 MB
    unsigned short* h = (unsigned short*)(ws + (4608 << 10)); // N*128*2 = 24.4 MB
    unsigned int* h2 = (unsigned int*)h;

    hipMemsetAsync(cnt, 0, (size_t)N * 4, stream);

    count_k<<<((E + 3) / 4 + 255) / 256, 256, 0, stream>>>(ei + E, cnt, E);
    int nb = (N + 1023) / 1024;
    scan_a<<<nb, 256, 0, stream>>>(cnt, rowstart, bsum, dinv, N);
    scan_bc<<<nb, 256, 0, stream>>>(rowstart, bsum, cursor, nb, N);
    int ntiles = (N + 63) / 64;
    int ngrid = ntiles < 768 ? ntiles : 768;
    gemm_mfma<<<ngrid, 256, 0, stream>>>(x, W, dinv, h, N, ntiles);
    fill_k<<<((E + 1) / 2 + 255) / 256, 256, 0, stream>>>(ei, cursor, eidx, E);
    agg_k<<<(N + 15) / 16, 256, 0, stream>>>(h2, x, b, dinv, rowstart, eidx, out, N);
}